// Round 4
// baseline (165.164 us; speedup 1.0000x reference)
//
#include <hip/hip_runtime.h>
#include <hip/hip_bf16.h>

// GQA prefill: B=2 T=2048 DM=768 H=12 HKV=4 DH=64 WIN=512 GLB=64
// 5 launches: prep(convert+rope) | transpose-all | fused QKV GEMM (rope fused,
// V transposed) | flash attn (swapped-QK^T lane-local softmax, in-register P
// redistribution via bpermute, defer-max, K dbuf) | out GEMM.

typedef __attribute__((ext_vector_type(8))) short bf16x8;
typedef __attribute__((ext_vector_type(4))) float f32x4;
typedef __attribute__((ext_vector_type(4))) unsigned short u16x4;

#define MFMA __builtin_amdgcn_mfma_f32_16x16x32_bf16

constexpr int BB = 2, TT = 2048, DM = 768, HH = 12, HKV = 4, DH = 64;
constexpr int WIN = 512, GLB = 64;
constexpr float SC2 = 0.18033688011112042f; // 0.125 * log2(e)

__device__ __forceinline__ unsigned short f2b(float f) {
    union { float f; unsigned int u; } v; v.f = f;
    unsigned int r = v.u + 0x7fffu + ((v.u >> 16) & 1u);
    return (unsigned short)(r >> 16);
}

// ---------- prep: x -> bf16 (blocks 0..3071), rope table (blocks 3072..3327)
__global__ __launch_bounds__(256) void k_prep(const float* __restrict__ x,
                                              unsigned short* __restrict__ xb,
                                              float2* __restrict__ rope) {
    int bid = blockIdx.x, tid = threadIdx.x;
    if (bid < 3072) {
        int i = bid * 256 + tid;
        float4 v = ((const float4*)x)[i];
        u16x4 o; o.x = f2b(v.x); o.y = f2b(v.y); o.z = f2b(v.z); o.w = f2b(v.w);
        ((u16x4*)xb)[i] = o;
    } else {
        int i = (bid - 3072) * 256 + tid;  // T*32
        int t = i >> 5, p = i & 31;
        float inv = exp2f(-(float)p * (13.287712379549449f / 32.0f)); // 10000^(-p/32)
        float ang = (float)t * inv;
        rope[i] = make_float2(cosf(ang), sinf(ang));
    }
}

// ---------- transpose all weights: f32 [K][N] -> bf16 [N][K], LDS 32x32 tiles
__global__ __launch_bounds__(256) void k_tw(const float* __restrict__ wq,
                                            const float* __restrict__ wk,
                                            const float* __restrict__ wv,
                                            const float* __restrict__ wo,
                                            unsigned short* __restrict__ wqT,
                                            unsigned short* __restrict__ wkT,
                                            unsigned short* __restrict__ wvT,
                                            unsigned short* __restrict__ woT) {
    __shared__ float t[32][33];
    int bid = blockIdx.x;
    const float* src; unsigned short* dst; int N, tile;
    if (bid < 576)      { src = wq; dst = wqT; N = 768; tile = bid; }
    else if (bid < 768) { src = wk; dst = wkT; N = 256; tile = bid - 576; }
    else if (bid < 960) { src = wv; dst = wvT; N = 256; tile = bid - 768; }
    else                { src = wo; dst = woT; N = 768; tile = bid - 960; }
    int ntiles = N / 32;
    int k0 = (tile / ntiles) * 32, n0 = (tile % ntiles) * 32;
    int tx = threadIdx.x & 31, ty = threadIdx.x >> 5;
    #pragma unroll
    for (int e = 0; e < 4; ++e) {
        int r = ty + e * 8;
        t[r][tx] = src[(size_t)(k0 + r) * N + n0 + tx];
    }
    __syncthreads();
    #pragma unroll
    for (int e = 0; e < 4; ++e) {
        int r = ty + e * 8;
        dst[(size_t)(n0 + r) * DM + k0 + tx] = f2b(t[tx][r]);
    }
}

// ---------- fused QKV projection GEMM: y<12 Q(rope), y<16 K(rope), else V(transposed)
__global__ __launch_bounds__(256) void k_qkv(const unsigned short* __restrict__ xb,
                                             const unsigned short* __restrict__ wqT,
                                             const unsigned short* __restrict__ wkT,
                                             const unsigned short* __restrict__ wvT,
                                             unsigned short* __restrict__ qb,
                                             unsigned short* __restrict__ kb,
                                             unsigned short* __restrict__ vtb,
                                             const float2* __restrict__ rope) {
    const int wave = threadIdx.x >> 6, lane = threadIdx.x & 63;
    const int quad = lane >> 4, col = lane & 15;
    const int y = blockIdx.y;
    const int m0 = blockIdx.x * 128 + wave * 32;
    int mode, hl;
    const unsigned short* Bt;
    if (y < 12)      { mode = 0; hl = y;      Bt = wqT + (size_t)hl * 64 * DM; }
    else if (y < 16) { mode = 1; hl = y - 12; Bt = wkT + (size_t)hl * 64 * DM; }
    else             { mode = 2; hl = y - 16; Bt = wvT + (size_t)hl * 64 * DM; }

    const unsigned short* ap = xb + (size_t)(m0 + col) * DM + quad * 8;
    const unsigned short* bp = Bt + (size_t)col * DM + quad * 8;

    f32x4 acc[2][4];
    #pragma unroll
    for (int rt = 0; rt < 2; ++rt)
        #pragma unroll
        for (int nt = 0; nt < 4; ++nt) acc[rt][nt] = f32x4{0.f, 0.f, 0.f, 0.f};

    #pragma unroll 4
    for (int k = 0; k < DM; k += 32) {
        bf16x8 a0 = *(const bf16x8*)(ap + k);
        bf16x8 a1 = *(const bf16x8*)(ap + 16 * DM + k);
        #pragma unroll
        for (int nt = 0; nt < 4; ++nt) {
            bf16x8 b = *(const bf16x8*)(bp + (size_t)nt * 16 * DM + k);
            acc[0][nt] = MFMA(a0, b, acc[0][nt], 0, 0, 0);
            acc[1][nt] = MFMA(a1, b, acc[1][nt], 0, 0, 0);
        }
    }

    if (mode == 2) {
        int b = m0 >> 11;
        #pragma unroll
        for (int nt = 0; nt < 4; ++nt)
            #pragma unroll
            for (int rt = 0; rt < 2; ++rt)
                #pragma unroll
                for (int r = 0; r < 4; ++r) {
                    int m = m0 + rt * 16 + quad * 4 + r;
                    int t = m & (TT - 1);
                    int d = nt * 16 + col;
                    vtb[((size_t)(b * HKV + hl) * DH + d) * TT + t] = f2b(acc[rt][nt][r]);
                }
        return;
    }
    int nheads = (mode == 0) ? HH : HKV;
    unsigned short* ob = (mode == 0) ? qb : kb;
    #pragma unroll
    for (int rt = 0; rt < 2; ++rt)
        #pragma unroll
        for (int r = 0; r < 4; ++r) {
            int m = m0 + rt * 16 + quad * 4 + r;
            int t = m & (TT - 1);
            int b = m >> 11;
            float2 cs0 = rope[t * 32 + col];
            float2 cs1 = rope[t * 32 + 16 + col];
            float v0 = acc[rt][0][r], v1 = acc[rt][1][r], v2 = acc[rt][2][r], v3 = acc[rt][3][r];
            unsigned short* dst = ob + ((size_t)(b * nheads + hl) * TT + t) * DH + col;
            dst[0]  = f2b(v0 * cs0.x - v2 * cs0.y);
            dst[16] = f2b(v1 * cs1.x - v3 * cs1.y);
            dst[32] = f2b(v2 * cs0.x + v0 * cs0.y);
            dst[48] = f2b(v3 * cs1.x + v1 * cs1.y);
        }
}

// ---------- output projection GEMM (f32 out)
__global__ __launch_bounds__(256) void k_out(const unsigned short* __restrict__ ao,
                                             const unsigned short* __restrict__ woT,
                                             float* __restrict__ out) {
    const int wave = threadIdx.x >> 6, lane = threadIdx.x & 63;
    const int quad = lane >> 4, col = lane & 15;
    const int m0 = blockIdx.x * 128 + wave * 32;
    const int n0 = blockIdx.y * 64;

    const unsigned short* ap = ao + (size_t)(m0 + col) * DM + quad * 8;
    const unsigned short* bp = woT + (size_t)(n0 + col) * DM + quad * 8;

    f32x4 acc[2][4];
    #pragma unroll
    for (int rt = 0; rt < 2; ++rt)
        #pragma unroll
        for (int nt = 0; nt < 4; ++nt) acc[rt][nt] = f32x4{0.f, 0.f, 0.f, 0.f};

    #pragma unroll 4
    for (int k = 0; k < DM; k += 32) {
        bf16x8 a0 = *(const bf16x8*)(ap + k);
        bf16x8 a1 = *(const bf16x8*)(ap + 16 * DM + k);
        #pragma unroll
        for (int nt = 0; nt < 4; ++nt) {
            bf16x8 b = *(const bf16x8*)(bp + (size_t)nt * 16 * DM + k);
            acc[0][nt] = MFMA(a0, b, acc[0][nt], 0, 0, 0);
            acc[1][nt] = MFMA(a1, b, acc[1][nt], 0, 0, 0);
        }
    }
    #pragma unroll
    for (int rt = 0; rt < 2; ++rt)
        #pragma unroll
        for (int nt = 0; nt < 4; ++nt)
            #pragma unroll
            for (int r = 0; r < 4; ++r) {
                int m = m0 + rt * 16 + quad * 4 + r;
                out[(size_t)m * DM + n0 + nt * 16 + col] = acc[rt][nt][r];
            }
}

// ---------- flash attention, swapped-QK^T: lane owns q-row i = i0+col.
// sT[f][r] = S[i0+col][j0+f*16+quad*4+r]; accO[dt][r] = O^T[dt*16+quad*4+r][col].
// P^T B-fragment built in-register: 8 cvt_pk + 16 bpermute + 8 cndmask per tile.
__global__ __launch_bounds__(256) void k_attn(const unsigned short* __restrict__ Q,
                                              const unsigned short* __restrict__ K,
                                              const unsigned short* __restrict__ Vt,
                                              unsigned short* __restrict__ AO) {
    const int lane = threadIdx.x & 63;
    const int wave = threadIdx.x >> 6;
    const int quad = lane >> 4, col = lane & 15;
    // bijective XCD swizzle: 768 blocks = 8 XCDs x 96
    const int lbid = (blockIdx.x & 7) * 96 + (blockIdx.x >> 3);
    const int qb = lbid & 31, bh = lbid >> 5;
    const int h = bh % HH, b = bh / HH;
    const int hkv = h / 3;
    const int i0 = qb * 64 + wave * 16;
    const int irow = i0 + col;

    const unsigned short* qbase = Q + ((size_t)(b * HH + h) * TT + irow) * DH + quad * 8;
    const bf16x8 qf0 = *(const bf16x8*)qbase;
    const bf16x8 qf1 = *(const bf16x8*)(qbase + 32);
    const unsigned short* kbase = K + (size_t)(b * HKV + hkv) * TT * DH;
    const unsigned short* vbase = Vt + (size_t)(b * HKV + hkv) * DH * TT;

    float m_run = -1e30f, l_lane = 0.f;
    f32x4 accO[4];
    #pragma unroll
    for (int dt = 0; dt < 4; ++dt) accO[dt] = f32x4{0.f, 0.f, 0.f, 0.f};

    int jw0 = (i0 - WIN + 1) & ~63; if (jw0 < 64) jw0 = 64;
    const int jlast = (i0 + 15) & ~63;
    const int nt = 1 + ((jlast >= jw0) ? (((jlast - jw0) >> 6) + 1) : 0);
    auto j0_of = [&](int t) { return (t == 0) ? 0 : (jw0 + ((t - 1) << 6)); };

    // bpermute source byte-addresses (lane*4) for P^T gather
    const int L0 = ((((quad * 2) & 3) << 4) | col) << 2;
    const int L1 = ((((quad * 2 + 1) & 3) << 4) | col) << 2;
    const bool hiq = quad >= 2;

    auto loadK = [&](int j0, bf16x8 (&kf)[8]) {
        const unsigned short* kp = kbase + (size_t)(j0 + col) * DH + quad * 8;
        #pragma unroll
        for (int f = 0; f < 4; ++f) {
            kf[f]     = *(const bf16x8*)(kp + (size_t)(f * 16) * DH);
            kf[4 + f] = *(const bf16x8*)(kp + (size_t)(f * 16) * DH + 32);
        }
    };

    auto tile_body = [&](int t, bf16x8 (&kc)[8], bf16x8 (&kn)[8]) {
        const int j0 = j0_of(t);
        const int mode = (t == 0) ? ((i0 < 64) ? 1 : 0)
                       : (((j0 + 63 > i0) || (j0 <= i0 + 15 - WIN)) ? 2 : 0);
        // V loads issued early (consumed by PV at tile end)
        bf16x8 vf[8];
        const unsigned short* vp = vbase + (size_t)col * TT + j0 + quad * 8;
        #pragma unroll
        for (int dt = 0; dt < 4; ++dt) {
            vf[dt]     = *(const bf16x8*)(vp + (size_t)(dt * 16) * TT);
            vf[4 + dt] = *(const bf16x8*)(vp + (size_t)(dt * 16) * TT + 32);
        }
        f32x4 sT[4];
        #pragma unroll
        for (int f = 0; f < 4; ++f) sT[f] = f32x4{0.f, 0.f, 0.f, 0.f};
        __builtin_amdgcn_s_setprio(1);
        #pragma unroll
        for (int f = 0; f < 4; ++f) {
            sT[f] = MFMA(kc[f], qf0, sT[f], 0, 0, 0);
            sT[f] = MFMA(kc[4 + f], qf1, sT[f], 0, 0, 0);
        }
        __builtin_amdgcn_s_setprio(0);
        if (t + 1 < nt) loadK(j0_of(t + 1), kn);   // K prefetch (double buffer)

        const int dq = irow - j0 - quad * 4;       // d = dq - f*16 - r
        if (mode == 1) {
            #pragma unroll
            for (int f = 0; f < 4; ++f)
                #pragma unroll
                for (int r = 0; r < 4; ++r)
                    if (dq - f * 16 - r < 0) sT[f][r] = -3e30f;
        } else if (mode == 2) {
            #pragma unroll
            for (int f = 0; f < 4; ++f)
                #pragma unroll
                for (int r = 0; r < 4; ++r)
                    if ((unsigned)(dq - f * 16 - r) >= (unsigned)WIN) sT[f][r] = -3e30f;
        }

        float mx = -3e30f;
        #pragma unroll
        for (int f = 0; f < 4; ++f)
            #pragma unroll
            for (int r = 0; r < 4; ++r) mx = fmaxf(mx, sT[f][r]);

        if (!__all(mx <= m_run + 44.f)) {          // defer-max: rare after tile 0
            float rm = fmaxf(mx, __shfl_xor(mx, 16));
            rm = fmaxf(rm, __shfl_xor(rm, 32));
            float mn = fmaxf(m_run, rm);
            float corr = exp2f((m_run - mn) * SC2);
            m_run = mn;
            l_lane *= corr;
            #pragma unroll
            for (int dt = 0; dt < 4; ++dt)
                #pragma unroll
                for (int r = 0; r < 4; ++r) accO[dt][r] *= corr;
        }

        const float mbase = m_run * SC2;
        unsigned int pk[4][2];
        float ps = 0.f;
        #pragma unroll
        for (int f = 0; f < 4; ++f) {
            float p0 = exp2f(__builtin_fmaf(sT[f][0], SC2, -mbase));
            float p1 = exp2f(__builtin_fmaf(sT[f][1], SC2, -mbase));
            float p2 = exp2f(__builtin_fmaf(sT[f][2], SC2, -mbase));
            float p3 = exp2f(__builtin_fmaf(sT[f][3], SC2, -mbase));
            ps += (p0 + p1) + (p2 + p3);
            asm("v_cvt_pk_bf16_f32 %0, %1, %2" : "=v"(pk[f][0]) : "v"(p0), "v"(p1));
            asm("v_cvt_pk_bf16_f32 %0, %1, %2" : "=v"(pk[f][1]) : "v"(p2), "v"(p3));
        }
        l_lane += ps;

        // P^T redistribution + PV, js = 0 then 1
        #pragma unroll
        for (int js = 0; js < 2; ++js) {
            int fa = 2 * js, fb = 2 * js + 1;
            unsigned int a0 = __builtin_amdgcn_ds_bpermute(L0, pk[fa][0]);
            unsigned int a1 = __builtin_amdgcn_ds_bpermute(L0, pk[fa][1]);
            unsigned int a2 = __builtin_amdgcn_ds_bpermute(L1, pk[fa][0]);
            unsigned int a3 = __builtin_amdgcn_ds_bpermute(L1, pk[fa][1]);
            unsigned int b0 = __builtin_amdgcn_ds_bpermute(L0, pk[fb][0]);
            unsigned int b1 = __builtin_amdgcn_ds_bpermute(L0, pk[fb][1]);
            unsigned int b2 = __builtin_amdgcn_ds_bpermute(L1, pk[fb][0]);
            unsigned int b3 = __builtin_amdgcn_ds_bpermute(L1, pk[fb][1]);
            union { bf16x8 v; unsigned int u[4]; } pb;
            pb.u[0] = hiq ? b0 : a0;
            pb.u[1] = hiq ? b1 : a1;
            pb.u[2] = hiq ? b2 : a2;
            pb.u[3] = hiq ? b3 : a3;
            __builtin_amdgcn_s_setprio(1);
            #pragma unroll
            for (int dt = 0; dt < 4; ++dt)
                accO[dt] = MFMA(vf[js * 4 + dt], pb.v, accO[dt], 0, 0, 0);
            __builtin_amdgcn_s_setprio(0);
        }
    };

    {
        bf16x8 kA[8], kB[8];
        loadK(0, kA);
        int t = 0;
        while (true) {
            tile_body(t, kA, kB); if (++t >= nt) break;
            tile_body(t, kB, kA); if (++t >= nt) break;
        }
    }

    float lr = l_lane;
    lr += __shfl_xor(lr, 16);
    lr += __shfl_xor(lr, 32);
    const float inv = 1.0f / lr;

    unsigned short* dst = AO + ((size_t)b * TT + irow) * DM + h * DH + quad * 4;
    #pragma unroll
    for (int dt = 0; dt < 4; ++dt) {
        u16x4 o;
        o.x = f2b(accO[dt][0] * inv);
        o.y = f2b(accO[dt][1] * inv);
        o.z = f2b(accO[dt][2] * inv);
        o.w = f2b(accO[dt][3] * inv);
        *(u16x4*)(dst + dt * 16) = o;
    }
}

extern "C" void kernel_launch(void* const* d_in, const int* in_sizes, int n_in,
                              void* d_out, int out_size, void* d_ws, size_t ws_size,
                              hipStream_t stream) {
    const float* x  = (const float*)d_in[0];
    const float* wq = (const float*)d_in[1];
    const float* wk = (const float*)d_in[2];
    const float* wv = (const float*)d_in[3];
    const float* wo = (const float*)d_in[4];
    float* out = (float*)d_out;

    char* ws = (char*)d_ws;
    size_t off = 0;
    auto alloc = [&](size_t bytes) -> void* {
        void* p = ws + off;
        off += (bytes + 255) & ~(size_t)255;
        return p;
    };
    const int M = BB * TT; // 4096
    unsigned short* xb  = (unsigned short*)alloc((size_t)M * DM * 2);
    unsigned short* wqT = (unsigned short*)alloc((size_t)DM * DM * 2);
    unsigned short* wkT = (unsigned short*)alloc((size_t)(HKV * DH) * DM * 2);
    unsigned short* wvT = (unsigned short*)alloc((size_t)(HKV * DH) * DM * 2);
    unsigned short* woT = (unsigned short*)alloc((size_t)DM * DM * 2);
    unsigned short* qb  = (unsigned short*)alloc((size_t)BB * HH * TT * DH * 2);
    unsigned short* kb  = (unsigned short*)alloc((size_t)BB * HKV * TT * DH * 2);
    unsigned short* vtb = (unsigned short*)alloc((size_t)BB * HKV * DH * TT * 2);
    unsigned short* ao  = (unsigned short*)alloc((size_t)M * DM * 2);
    float2* rope        = (float2*)alloc((size_t)TT * 32 * sizeof(float2));

    k_prep<<<3328, 256, 0, stream>>>(x, xb, rope);
    k_tw<<<1536, 256, 0, stream>>>(wq, wk, wv, wo, wqT, wkT, wvT, woT);
    k_qkv<<<dim3(M / 128, 20), 256, 0, stream>>>(xb, wqT, wkT, wvT, qb, kb, vtb, rope);
    k_attn<<<768, 256, 0, stream>>>(qb, kb, vtb, ao);
    k_out<<<dim3(M / 128, 12), 256, 0, stream>>>(ao, woT, out);
}

// Round 5
// 129.571 us; speedup vs baseline: 1.2747x; 1.2747x over previous
//
#include <hip/hip_runtime.h>
#include <hip/hip_bf16.h>

// GQA prefill: B=2 T=2048 DM=768 H=12 HKV=4 DH=64 WIN=512 GLB=64
// 5 launches: prep(convert+rope) | transpose-all | fused QKV GEMM (rope fused,
// V transposed) | flash attn (cooperative LDS-staged KV double-buffer,
// swapped-QK^T lane-local softmax, bpermute P-transpose, defer-max) | out GEMM.

typedef __attribute__((ext_vector_type(8))) short bf16x8;
typedef __attribute__((ext_vector_type(4))) float f32x4;
typedef __attribute__((ext_vector_type(4))) unsigned short u16x4;

#define MFMA __builtin_amdgcn_mfma_f32_16x16x32_bf16

constexpr int BB = 2, TT = 2048, DM = 768, HH = 12, HKV = 4, DH = 64;
constexpr int WIN = 512, GLB = 64;
constexpr float SC2 = 0.18033688011112042f; // 0.125 * log2(e)

__device__ __forceinline__ unsigned short f2b(float f) {
    union { float f; unsigned int u; } v; v.f = f;
    unsigned int r = v.u + 0x7fffu + ((v.u >> 16) & 1u);
    return (unsigned short)(r >> 16);
}

// ---------- prep: x -> bf16 (blocks 0..3071), rope table (blocks 3072..3327)
__global__ __launch_bounds__(256) void k_prep(const float* __restrict__ x,
                                              unsigned short* __restrict__ xb,
                                              float2* __restrict__ rope) {
    int bid = blockIdx.x, tid = threadIdx.x;
    if (bid < 3072) {
        int i = bid * 256 + tid;
        float4 v = ((const float4*)x)[i];
        u16x4 o; o.x = f2b(v.x); o.y = f2b(v.y); o.z = f2b(v.z); o.w = f2b(v.w);
        ((u16x4*)xb)[i] = o;
    } else {
        int i = (bid - 3072) * 256 + tid;  // T*32
        int t = i >> 5, p = i & 31;
        float inv = exp2f(-(float)p * (13.287712379549449f / 32.0f)); // 10000^(-p/32)
        float ang = (float)t * inv;
        rope[i] = make_float2(cosf(ang), sinf(ang));
    }
}

// ---------- transpose all weights: f32 [K][N] -> bf16 [N][K], LDS 32x32 tiles
__global__ __launch_bounds__(256) void k_tw(const float* __restrict__ wq,
                                            const float* __restrict__ wk,
                                            const float* __restrict__ wv,
                                            const float* __restrict__ wo,
                                            unsigned short* __restrict__ wqT,
                                            unsigned short* __restrict__ wkT,
                                            unsigned short* __restrict__ wvT,
                                            unsigned short* __restrict__ woT) {
    __shared__ float t[32][33];
    int bid = blockIdx.x;
    const float* src; unsigned short* dst; int N, tile;
    if (bid < 576)      { src = wq; dst = wqT; N = 768; tile = bid; }
    else if (bid < 768) { src = wk; dst = wkT; N = 256; tile = bid - 576; }
    else if (bid < 960) { src = wv; dst = wvT; N = 256; tile = bid - 768; }
    else                { src = wo; dst = woT; N = 768; tile = bid - 960; }
    int ntiles = N / 32;
    int k0 = (tile / ntiles) * 32, n0 = (tile % ntiles) * 32;
    int tx = threadIdx.x & 31, ty = threadIdx.x >> 5;
    #pragma unroll
    for (int e = 0; e < 4; ++e) {
        int r = ty + e * 8;
        t[r][tx] = src[(size_t)(k0 + r) * N + n0 + tx];
    }
    __syncthreads();
    #pragma unroll
    for (int e = 0; e < 4; ++e) {
        int r = ty + e * 8;
        dst[(size_t)(n0 + r) * DM + k0 + tx] = f2b(t[tx][r]);
    }
}

// ---------- fused QKV projection GEMM: y<12 Q(rope), y<16 K(rope), else V(transposed)
__global__ __launch_bounds__(256) void k_qkv(const unsigned short* __restrict__ xb,
                                             const unsigned short* __restrict__ wqT,
                                             const unsigned short* __restrict__ wkT,
                                             const unsigned short* __restrict__ wvT,
                                             unsigned short* __restrict__ qb,
                                             unsigned short* __restrict__ kb,
                                             unsigned short* __restrict__ vtb,
                                             const float2* __restrict__ rope) {
    const int wave = threadIdx.x >> 6, lane = threadIdx.x & 63;
    const int quad = lane >> 4, col = lane & 15;
    const int y = blockIdx.y;
    const int m0 = blockIdx.x * 128 + wave * 32;
    int mode, hl;
    const unsigned short* Bt;
    if (y < 12)      { mode = 0; hl = y;      Bt = wqT + (size_t)hl * 64 * DM; }
    else if (y < 16) { mode = 1; hl = y - 12; Bt = wkT + (size_t)hl * 64 * DM; }
    else             { mode = 2; hl = y - 16; Bt = wvT + (size_t)hl * 64 * DM; }

    const unsigned short* ap = xb + (size_t)(m0 + col) * DM + quad * 8;
    const unsigned short* bp = Bt + (size_t)col * DM + quad * 8;

    f32x4 acc[2][4];
    #pragma unroll
    for (int rt = 0; rt < 2; ++rt)
        #pragma unroll
        for (int nt = 0; nt < 4; ++nt) acc[rt][nt] = f32x4{0.f, 0.f, 0.f, 0.f};

    #pragma unroll 4
    for (int k = 0; k < DM; k += 32) {
        bf16x8 a0 = *(const bf16x8*)(ap + k);
        bf16x8 a1 = *(const bf16x8*)(ap + 16 * DM + k);
        #pragma unroll
        for (int nt = 0; nt < 4; ++nt) {
            bf16x8 b = *(const bf16x8*)(bp + (size_t)nt * 16 * DM + k);
            acc[0][nt] = MFMA(a0, b, acc[0][nt], 0, 0, 0);
            acc[1][nt] = MFMA(a1, b, acc[1][nt], 0, 0, 0);
        }
    }

    if (mode == 2) {
        int b = m0 >> 11;
        #pragma unroll
        for (int nt = 0; nt < 4; ++nt)
            #pragma unroll
            for (int rt = 0; rt < 2; ++rt)
                #pragma unroll
                for (int r = 0; r < 4; ++r) {
                    int m = m0 + rt * 16 + quad * 4 + r;
                    int t = m & (TT - 1);
                    int d = nt * 16 + col;
                    vtb[((size_t)(b * HKV + hl) * DH + d) * TT + t] = f2b(acc[rt][nt][r]);
                }
        return;
    }
    int nheads = (mode == 0) ? HH : HKV;
    unsigned short* ob = (mode == 0) ? qb : kb;
    #pragma unroll
    for (int rt = 0; rt < 2; ++rt)
        #pragma unroll
        for (int r = 0; r < 4; ++r) {
            int m = m0 + rt * 16 + quad * 4 + r;
            int t = m & (TT - 1);
            int b = m >> 11;
            float2 cs0 = rope[t * 32 + col];
            float2 cs1 = rope[t * 32 + 16 + col];
            float v0 = acc[rt][0][r], v1 = acc[rt][1][r], v2 = acc[rt][2][r], v3 = acc[rt][3][r];
            unsigned short* dst = ob + ((size_t)(b * nheads + hl) * TT + t) * DH + col;
            dst[0]  = f2b(v0 * cs0.x - v2 * cs0.y);
            dst[16] = f2b(v1 * cs1.x - v3 * cs1.y);
            dst[32] = f2b(v2 * cs0.x + v0 * cs0.y);
            dst[48] = f2b(v3 * cs1.x + v1 * cs1.y);
        }
}

// ---------- output projection GEMM (f32 out)
__global__ __launch_bounds__(256) void k_out(const unsigned short* __restrict__ ao,
                                             const unsigned short* __restrict__ woT,
                                             float* __restrict__ out) {
    const int wave = threadIdx.x >> 6, lane = threadIdx.x & 63;
    const int quad = lane >> 4, col = lane & 15;
    const int m0 = blockIdx.x * 128 + wave * 32;
    const int n0 = blockIdx.y * 64;

    const unsigned short* ap = ao + (size_t)(m0 + col) * DM + quad * 8;
    const unsigned short* bp = woT + (size_t)(n0 + col) * DM + quad * 8;

    f32x4 acc[2][4];
    #pragma unroll
    for (int rt = 0; rt < 2; ++rt)
        #pragma unroll
        for (int nt = 0; nt < 4; ++nt) acc[rt][nt] = f32x4{0.f, 0.f, 0.f, 0.f};

    #pragma unroll 4
    for (int k = 0; k < DM; k += 32) {
        bf16x8 a0 = *(const bf16x8*)(ap + k);
        bf16x8 a1 = *(const bf16x8*)(ap + 16 * DM + k);
        #pragma unroll
        for (int nt = 0; nt < 4; ++nt) {
            bf16x8 b = *(const bf16x8*)(bp + (size_t)nt * 16 * DM + k);
            acc[0][nt] = MFMA(a0, b, acc[0][nt], 0, 0, 0);
            acc[1][nt] = MFMA(a1, b, acc[1][nt], 0, 0, 0);
        }
    }
    #pragma unroll
    for (int rt = 0; rt < 2; ++rt)
        #pragma unroll
        for (int nt = 0; nt < 4; ++nt)
            #pragma unroll
            for (int r = 0; r < 4; ++r) {
                int m = m0 + rt * 16 + quad * 4 + r;
                out[(size_t)m * DM + n0 + nt * 16 + col] = acc[rt][nt][r];
            }
}

// ---------- flash attention, cooperative LDS KV staging + swapped-QK^T.
// Block = 64 q-rows (4 waves x 16). All 4 waves share an IDENTICAL KV tile list
// ((i0+16w-511)&~63 is w-invariant), so K/V tiles are staged once per block into
// double-buffered LDS (reg-staged: loads issued at iter top, ds_write after
// compute, one barrier per tile). Lane owns q-row i=i0+col (swapped MFMA);
// P^T rebuilt in-register via 8 cvt_pk + 16 bpermute + 8 cndmask per tile.
__global__ __launch_bounds__(256) void k_attn(const unsigned short* __restrict__ Q,
                                              const unsigned short* __restrict__ K,
                                              const unsigned short* __restrict__ Vt,
                                              unsigned short* __restrict__ AO) {
    __shared__ __align__(16) unsigned short kbuf[2][64 * 64]; // [buf][j][d] 8KB
    __shared__ __align__(16) unsigned short vbuf[2][64 * 64]; // [buf][d][j] 8KB
    const int lane = threadIdx.x & 63;
    const int wave = threadIdx.x >> 6;
    const int quad = lane >> 4, col = lane & 15;
    // bijective XCD swizzle: 768 blocks = 8 XCDs x 96
    const int lbid = (blockIdx.x & 7) * 96 + (blockIdx.x >> 3);
    const int qb = lbid & 31, bh = lbid >> 5;
    const int h = bh % HH, b = bh / HH;
    const int hkv = h / 3;
    const int i0 = qb * 64 + wave * 16;
    const int irow = i0 + col;

    const unsigned short* qbase = Q + ((size_t)(b * HH + h) * TT + irow) * DH + quad * 8;
    const bf16x8 qf0 = *(const bf16x8*)qbase;
    const bf16x8 qf1 = *(const bf16x8*)(qbase + 32);
    const unsigned short* kbase = K + (size_t)(b * HKV + hkv) * TT * DH;
    const unsigned short* vbase = Vt + (size_t)(b * HKV + hkv) * DH * TT;

    float m_run = -1e30f, l_lane = 0.f;
    f32x4 accO[4];
    #pragma unroll
    for (int dt = 0; dt < 4; ++dt) accO[dt] = f32x4{0.f, 0.f, 0.f, 0.f};

    // block-uniform tile list (identical for all 4 waves)
    int jw0 = (qb * 64 - WIN + 1) & ~63; if (jw0 < 64) jw0 = 64;
    const int jlast = qb * 64;
    const int nt = 1 + ((jlast >= 64) ? (((jlast - jw0) >> 6) + 1) : 0);
    auto j0_of = [&](int t) { return (t == 0) ? 0 : (jw0 + ((t - 1) << 6)); };

    // staging geometry: wave stages K rows [16w,16w+16) and V d-rows [16w,16w+16)
    const int srow = wave * 16 + (lane >> 3);
    const int sq = lane & 7;

    // bpermute source byte-addresses (lane*4) for P^T gather
    const int L0 = ((((quad * 2) & 3) << 4) | col) << 2;
    const int L1 = ((((quad * 2 + 1) & 3) << 4) | col) << 2;
    const bool hiq = quad >= 2;

    uint4 g0, g1, g2, g3;
    auto stage_load = [&](int j0) {
        const unsigned short* ks = kbase + (size_t)(j0 + srow) * DH + sq * 8;
        const unsigned short* vs = vbase + (size_t)srow * TT + j0 + sq * 8;
        g0 = *(const uint4*)ks;
        g1 = *(const uint4*)(ks + 8 * DH);
        g2 = *(const uint4*)vs;
        g3 = *(const uint4*)(vs + 8 * TT);
    };
    auto stage_write = [&](int bb) {
        unsigned short* kd = &kbuf[bb][srow * 64 + sq * 8];
        unsigned short* vd = &vbuf[bb][srow * 64 + sq * 8];
        *(uint4*)kd = g0;
        *(uint4*)(kd + 8 * 64) = g1;
        *(uint4*)vd = g2;
        *(uint4*)(vd + 8 * 64) = g3;
    };

    stage_load(0);
    stage_write(0);
    __syncthreads();

    for (int t = 0; t < nt; ++t) {
        const int bb = t & 1;
        const bool more = (t + 1) < nt;
        if (more) stage_load(j0_of(t + 1));   // issue-early (T14)

        const int j0 = j0_of(t);
        const int mode = (t == 0) ? ((i0 < 64) ? 1 : 0)
                       : (((j0 + 63 > i0) || (j0 <= i0 + 15 - WIN)) ? 2 : 0);

        // QK^T (swapped): sT[f][r] = S[irow][j0+f*16+quad*4+r]
        f32x4 sT[4];
        #pragma unroll
        for (int f = 0; f < 4; ++f) sT[f] = f32x4{0.f, 0.f, 0.f, 0.f};
        __builtin_amdgcn_s_setprio(1);
        #pragma unroll
        for (int f = 0; f < 4; ++f) {
            bf16x8 k0 = *(const bf16x8*)&kbuf[bb][(f * 16 + col) * 64 + quad * 8];
            bf16x8 k1 = *(const bf16x8*)&kbuf[bb][(f * 16 + col) * 64 + 32 + quad * 8];
            sT[f] = MFMA(k0, qf0, sT[f], 0, 0, 0);
            sT[f] = MFMA(k1, qf1, sT[f], 0, 0, 0);
        }
        __builtin_amdgcn_s_setprio(0);

        const int dq = irow - j0 - quad * 4;  // d = dq - f*16 - r
        if (mode == 1) {
            #pragma unroll
            for (int f = 0; f < 4; ++f)
                #pragma unroll
                for (int r = 0; r < 4; ++r)
                    if (dq - f * 16 - r < 0) sT[f][r] = -3e30f;
        } else if (mode == 2) {
            #pragma unroll
            for (int f = 0; f < 4; ++f)
                #pragma unroll
                for (int r = 0; r < 4; ++r)
                    if ((unsigned)(dq - f * 16 - r) >= (unsigned)WIN) sT[f][r] = -3e30f;
        }

        float mx = -3e30f;
        #pragma unroll
        for (int f = 0; f < 4; ++f)
            #pragma unroll
            for (int r = 0; r < 4; ++r) mx = fmaxf(mx, sT[f][r]);

        if (!__all(mx <= m_run + 44.f)) {     // defer-max: rare after tile 0
            float rm = fmaxf(mx, __shfl_xor(mx, 16));
            rm = fmaxf(rm, __shfl_xor(rm, 32));
            float mn = fmaxf(m_run, rm);
            float corr = exp2f((m_run - mn) * SC2);
            m_run = mn;
            l_lane *= corr;
            #pragma unroll
            for (int dt = 0; dt < 4; ++dt)
                #pragma unroll
                for (int r = 0; r < 4; ++r) accO[dt][r] *= corr;
        }

        const float mbase = m_run * SC2;
        unsigned int pk[4][2];
        float ps = 0.f;
        #pragma unroll
        for (int f = 0; f < 4; ++f) {
            float p0 = exp2f(__builtin_fmaf(sT[f][0], SC2, -mbase));
            float p1 = exp2f(__builtin_fmaf(sT[f][1], SC2, -mbase));
            float p2 = exp2f(__builtin_fmaf(sT[f][2], SC2, -mbase));
            float p3 = exp2f(__builtin_fmaf(sT[f][3], SC2, -mbase));
            ps += (p0 + p1) + (p2 + p3);
            asm("v_cvt_pk_bf16_f32 %0, %1, %2" : "=v"(pk[f][0]) : "v"(p0), "v"(p1));
            asm("v_cvt_pk_bf16_f32 %0, %1, %2" : "=v"(pk[f][1]) : "v"(p2), "v"(p3));
        }
        l_lane += ps;

        // V fragments from LDS (issued here; consumed under bpermute latency)
        bf16x8 vf[8];
        #pragma unroll
        for (int js = 0; js < 2; ++js)
            #pragma unroll
            for (int dt = 0; dt < 4; ++dt)
                vf[js * 4 + dt] =
                    *(const bf16x8*)&vbuf[bb][(dt * 16 + col) * 64 + js * 32 + quad * 8];

        // P^T redistribution + PV, js = 0 then 1
        #pragma unroll
        for (int js = 0; js < 2; ++js) {
            int fa = 2 * js, fb = 2 * js + 1;
            unsigned int a0 = __builtin_amdgcn_ds_bpermute(L0, pk[fa][0]);
            unsigned int a1 = __builtin_amdgcn_ds_bpermute(L0, pk[fa][1]);
            unsigned int a2 = __builtin_amdgcn_ds_bpermute(L1, pk[fa][0]);
            unsigned int a3 = __builtin_amdgcn_ds_bpermute(L1, pk[fa][1]);
            unsigned int b0 = __builtin_amdgcn_ds_bpermute(L0, pk[fb][0]);
            unsigned int b1 = __builtin_amdgcn_ds_bpermute(L0, pk[fb][1]);
            unsigned int b2 = __builtin_amdgcn_ds_bpermute(L1, pk[fb][0]);
            unsigned int b3 = __builtin_amdgcn_ds_bpermute(L1, pk[fb][1]);
            union { bf16x8 v; unsigned int u[4]; } pb;
            pb.u[0] = hiq ? b0 : a0;
            pb.u[1] = hiq ? b1 : a1;
            pb.u[2] = hiq ? b2 : a2;
            pb.u[3] = hiq ? b3 : a3;
            __builtin_amdgcn_s_setprio(1);
            #pragma unroll
            for (int dt = 0; dt < 4; ++dt)
                accO[dt] = MFMA(vf[js * 4 + dt], pb.v, accO[dt], 0, 0, 0);
            __builtin_amdgcn_s_setprio(0);
        }

        if (more) stage_write(bb ^ 1);        // write-late (after vmcnt drain)
        __syncthreads();
    }

    float lr = l_lane;
    lr += __shfl_xor(lr, 16);
    lr += __shfl_xor(lr, 32);
    const float inv = 1.0f / lr;

    unsigned short* dst = AO + ((size_t)b * TT + irow) * DM + h * DH + quad * 4;
    #pragma unroll
    for (int dt = 0; dt < 4; ++dt) {
        u16x4 o;
        o.x = f2b(accO[dt][0] * inv);
        o.y = f2b(accO[dt][1] * inv);
        o.z = f2b(accO[dt][2] * inv);
        o.w = f2b(accO[dt][3] * inv);
        *(u16x4*)(dst + dt * 16) = o;
    }
}

extern "C" void kernel_launch(void* const* d_in, const int* in_sizes, int n_in,
                              void* d_out, int out_size, void* d_ws, size_t ws_size,
                              hipStream_t stream) {
    const float* x  = (const float*)d_in[0];
    const float* wq = (const float*)d_in[1];
    const float* wk = (const float*)d_in[2];
    const float* wv = (const float*)d_in[3];
    const float* wo = (const float*)d_in[4];
    float* out = (float*)d_out;

    char* ws = (char*)d_ws;
    size_t off = 0;
    auto alloc = [&](size_t bytes) -> void* {
        void* p = ws + off;
        off += (bytes + 255) & ~(size_t)255;
        return p;
    };
    const int M = BB * TT; // 4096
    unsigned short* xb  = (unsigned short*)alloc((size_t)M * DM * 2);
    unsigned short* wqT = (unsigned short*)alloc((size_t)DM * DM * 2);
    unsigned short* wkT = (unsigned short*)alloc((size_t)(HKV * DH) * DM * 2);
    unsigned short* wvT = (unsigned short*)alloc((size_t)(HKV * DH) * DM * 2);
    unsigned short* woT = (unsigned short*)alloc((size_t)DM * DM * 2);
    unsigned short* qb  = (unsigned short*)alloc((size_t)BB * HH * TT * DH * 2);
    unsigned short* kb  = (unsigned short*)alloc((size_t)BB * HKV * TT * DH * 2);
    unsigned short* vtb = (unsigned short*)alloc((size_t)BB * HKV * DH * TT * 2);
    unsigned short* ao  = (unsigned short*)alloc((size_t)M * DM * 2);
    float2* rope        = (float2*)alloc((size_t)TT * 32 * sizeof(float2));

    k_prep<<<3328, 256, 0, stream>>>(x, xb, rope);
    k_tw<<<1536, 256, 0, stream>>>(wq, wk, wv, wo, wqT, wkT, wvT, woT);
    k_qkv<<<dim3(M / 128, 20), 256, 0, stream>>>(xb, wqT, wkT, wvT, qb, kb, vtb, rope);
    k_attn<<<768, 256, 0, stream>>>(qb, kb, vtb, ao);
    k_out<<<dim3(M / 128, 12), 256, 0, stream>>>(ao, woT, out);
}

// Round 6
// 75.335 us; speedup vs baseline: 2.1924x; 1.7199x over previous
//
#include <hip/hip_runtime.h>
#include <hip/hip_bf16.h>

// GQA prefill: B=2 T=2048 DM=768 H=12 HKV=4 DH=64 WIN=512 GLB=64
// 5 launches: prep(convert+rope) | transpose-all | fused QKV GEMM (LDS-staged
// global_load_lds double-buffer, rope fused, V transposed) | flash attn
// (cooperative LDS KV staging, swapped-QK^T, bpermute P-transpose) | out GEMM.

typedef __attribute__((ext_vector_type(8))) short bf16x8;
typedef __attribute__((ext_vector_type(4))) float f32x4;
typedef __attribute__((ext_vector_type(4))) unsigned short u16x4;

#define MFMA __builtin_amdgcn_mfma_f32_16x16x32_bf16

constexpr int BB = 2, TT = 2048, DM = 768, HH = 12, HKV = 4, DH = 64;
constexpr int WIN = 512, GLB = 64;
constexpr float SC2 = 0.18033688011112042f; // 0.125 * log2(e)

__device__ __forceinline__ unsigned short f2b(float f) {
    union { float f; unsigned int u; } v; v.f = f;
    unsigned int r = v.u + 0x7fffu + ((v.u >> 16) & 1u);
    return (unsigned short)(r >> 16);
}

#define GLOAD_LDS(gp, lp)                                                      \
    __builtin_amdgcn_global_load_lds(                                          \
        (const __attribute__((address_space(1))) void*)(gp),                   \
        (__attribute__((address_space(3))) void*)(lp), 16, 0, 0)

// ---------- prep: x -> bf16 (blocks 0..3071), rope table (blocks 3072..3327)
__global__ __launch_bounds__(256) void k_prep(const float* __restrict__ x,
                                              unsigned short* __restrict__ xb,
                                              float2* __restrict__ rope) {
    int bid = blockIdx.x, tid = threadIdx.x;
    if (bid < 3072) {
        int i = bid * 256 + tid;
        float4 v = ((const float4*)x)[i];
        u16x4 o; o.x = f2b(v.x); o.y = f2b(v.y); o.z = f2b(v.z); o.w = f2b(v.w);
        ((u16x4*)xb)[i] = o;
    } else {
        int i = (bid - 3072) * 256 + tid;  // T*32
        int t = i >> 5, p = i & 31;
        float inv = exp2f(-(float)p * (13.287712379549449f / 32.0f)); // 10000^(-p/32)
        float ang = (float)t * inv;
        rope[i] = make_float2(cosf(ang), sinf(ang));
    }
}

// ---------- transpose all weights: f32 [K][N] -> bf16 [N][K], LDS 32x32 tiles
__global__ __launch_bounds__(256) void k_tw(const float* __restrict__ wq,
                                            const float* __restrict__ wk,
                                            const float* __restrict__ wv,
                                            const float* __restrict__ wo,
                                            unsigned short* __restrict__ wqT,
                                            unsigned short* __restrict__ wkT,
                                            unsigned short* __restrict__ wvT,
                                            unsigned short* __restrict__ woT) {
    __shared__ float t[32][33];
    int bid = blockIdx.x;
    const float* src; unsigned short* dst; int N, tile;
    if (bid < 576)      { src = wq; dst = wqT; N = 768; tile = bid; }
    else if (bid < 768) { src = wk; dst = wkT; N = 256; tile = bid - 576; }
    else if (bid < 960) { src = wv; dst = wvT; N = 256; tile = bid - 768; }
    else                { src = wo; dst = woT; N = 768; tile = bid - 960; }
    int ntiles = N / 32;
    int k0 = (tile / ntiles) * 32, n0 = (tile % ntiles) * 32;
    int tx = threadIdx.x & 31, ty = threadIdx.x >> 5;
    #pragma unroll
    for (int e = 0; e < 4; ++e) {
        int r = ty + e * 8;
        t[r][tx] = src[(size_t)(k0 + r) * N + n0 + tx];
    }
    __syncthreads();
    #pragma unroll
    for (int e = 0; e < 4; ++e) {
        int r = ty + e * 8;
        dst[(size_t)(n0 + r) * DM + k0 + tx] = f2b(t[tx][r]);
    }
}

// ---------- fused QKV projection GEMM, LDS-staged double-buffer.
// Tile 128(M)x64(N), BK=32, K=768 -> 24 steps. y<12 Q(rope), y<16 K(rope), else V^T.
__global__ __launch_bounds__(256) void k_qkv(const unsigned short* __restrict__ xb,
                                             const unsigned short* __restrict__ wqT,
                                             const unsigned short* __restrict__ wkT,
                                             const unsigned short* __restrict__ wvT,
                                             unsigned short* __restrict__ qb,
                                             unsigned short* __restrict__ kb,
                                             unsigned short* __restrict__ vtb,
                                             const float2* __restrict__ rope) {
    __shared__ __align__(16) unsigned short Ab[2][128 * 32]; // [buf][row][k] 8KB each
    __shared__ __align__(16) unsigned short Bbuf[2][64 * 32];
    const int tid = threadIdx.x;
    const int wave = tid >> 6, lane = tid & 63;
    const int quad = lane >> 4, col = lane & 15;
    const int y = blockIdx.y;
    int mode, hl;
    const unsigned short* Bt;
    if (y < 12)      { mode = 0; hl = y;      Bt = wqT + (size_t)hl * 64 * DM; }
    else if (y < 16) { mode = 1; hl = y - 12; Bt = wkT + (size_t)hl * 64 * DM; }
    else             { mode = 2; hl = y - 16; Bt = wvT + (size_t)hl * 64 * DM; }
    const int m0b = blockIdx.x * 128;

    // staging: lane -> (row = lane/4, 16B chunk = lane%4); LDS linear = lane*16
    const int sr = lane >> 2, sc = (lane & 3) * 8;
    const unsigned short* gA0 = xb + (size_t)(m0b + wave * 32 + sr) * DM + sc;
    const unsigned short* gA1 = gA0 + (size_t)16 * DM;
    const unsigned short* gB  = Bt + (size_t)(wave * 16 + sr) * DM + sc;

    f32x4 acc[2][4];
    #pragma unroll
    for (int rt = 0; rt < 2; ++rt)
        #pragma unroll
        for (int nt = 0; nt < 4; ++nt) acc[rt][nt] = f32x4{0.f, 0.f, 0.f, 0.f};

    GLOAD_LDS(gA0, &Ab[0][wave * 1024]);
    GLOAD_LDS(gA1, &Ab[0][wave * 1024 + 512]);
    GLOAD_LDS(gB,  &Bbuf[0][wave * 512]);
    __syncthreads();

    for (int t = 0; t < 24; ++t) {
        const int buf = t & 1;
        if (t < 23) {
            const int kn = (t + 1) * 32;
            GLOAD_LDS(gA0 + kn, &Ab[buf ^ 1][wave * 1024]);
            GLOAD_LDS(gA1 + kn, &Ab[buf ^ 1][wave * 1024 + 512]);
            GLOAD_LDS(gB + kn,  &Bbuf[buf ^ 1][wave * 512]);
        }
        bf16x8 a0 = *(const bf16x8*)&Ab[buf][(wave * 32 + col) * 32 + quad * 8];
        bf16x8 a1 = *(const bf16x8*)&Ab[buf][(wave * 32 + 16 + col) * 32 + quad * 8];
        __builtin_amdgcn_s_setprio(1);
        #pragma unroll
        for (int nt = 0; nt < 4; ++nt) {
            bf16x8 b = *(const bf16x8*)&Bbuf[buf][(nt * 16 + col) * 32 + quad * 8];
            acc[0][nt] = MFMA(a0, b, acc[0][nt], 0, 0, 0);
            acc[1][nt] = MFMA(a1, b, acc[1][nt], 0, 0, 0);
        }
        __builtin_amdgcn_s_setprio(0);
        __syncthreads();   // drains vmcnt (staged tile ready) + lgkm
    }

    if (mode == 2) {
        int b = m0b >> 11;
        #pragma unroll
        for (int nt = 0; nt < 4; ++nt)
            #pragma unroll
            for (int rt = 0; rt < 2; ++rt)
                #pragma unroll
                for (int r = 0; r < 4; ++r) {
                    int m = m0b + wave * 32 + rt * 16 + quad * 4 + r;
                    int t = m & (TT - 1);
                    int d = nt * 16 + col;
                    vtb[((size_t)(b * HKV + hl) * DH + d) * TT + t] = f2b(acc[rt][nt][r]);
                }
        return;
    }
    int nheads = (mode == 0) ? HH : HKV;
    unsigned short* ob = (mode == 0) ? qb : kb;
    #pragma unroll
    for (int rt = 0; rt < 2; ++rt)
        #pragma unroll
        for (int r = 0; r < 4; ++r) {
            int m = m0b + wave * 32 + rt * 16 + quad * 4 + r;
            int t = m & (TT - 1);
            int b = m >> 11;
            float2 cs0 = rope[t * 32 + col];
            float2 cs1 = rope[t * 32 + 16 + col];
            float v0 = acc[rt][0][r], v1 = acc[rt][1][r], v2 = acc[rt][2][r], v3 = acc[rt][3][r];
            unsigned short* dst = ob + ((size_t)(b * nheads + hl) * TT + t) * DH + col;
            dst[0]  = f2b(v0 * cs0.x - v2 * cs0.y);
            dst[16] = f2b(v1 * cs1.x - v3 * cs1.y);
            dst[32] = f2b(v2 * cs0.x + v0 * cs0.y);
            dst[48] = f2b(v3 * cs1.x + v1 * cs1.y);
        }
}

// ---------- output projection GEMM (f32 out), same staged structure
__global__ __launch_bounds__(256) void k_out(const unsigned short* __restrict__ ao,
                                             const unsigned short* __restrict__ woT,
                                             float* __restrict__ out) {
    __shared__ __align__(16) unsigned short Ab[2][128 * 32];
    __shared__ __align__(16) unsigned short Bbuf[2][64 * 32];
    const int tid = threadIdx.x;
    const int wave = tid >> 6, lane = tid & 63;
    const int quad = lane >> 4, col = lane & 15;
    const int m0b = blockIdx.x * 128;
    const int n0 = blockIdx.y * 64;

    const int sr = lane >> 2, sc = (lane & 3) * 8;
    const unsigned short* gA0 = ao + (size_t)(m0b + wave * 32 + sr) * DM + sc;
    const unsigned short* gA1 = gA0 + (size_t)16 * DM;
    const unsigned short* gB  = woT + (size_t)(n0 + wave * 16 + sr) * DM + sc;

    f32x4 acc[2][4];
    #pragma unroll
    for (int rt = 0; rt < 2; ++rt)
        #pragma unroll
        for (int nt = 0; nt < 4; ++nt) acc[rt][nt] = f32x4{0.f, 0.f, 0.f, 0.f};

    GLOAD_LDS(gA0, &Ab[0][wave * 1024]);
    GLOAD_LDS(gA1, &Ab[0][wave * 1024 + 512]);
    GLOAD_LDS(gB,  &Bbuf[0][wave * 512]);
    __syncthreads();

    for (int t = 0; t < 24; ++t) {
        const int buf = t & 1;
        if (t < 23) {
            const int kn = (t + 1) * 32;
            GLOAD_LDS(gA0 + kn, &Ab[buf ^ 1][wave * 1024]);
            GLOAD_LDS(gA1 + kn, &Ab[buf ^ 1][wave * 1024 + 512]);
            GLOAD_LDS(gB + kn,  &Bbuf[buf ^ 1][wave * 512]);
        }
        bf16x8 a0 = *(const bf16x8*)&Ab[buf][(wave * 32 + col) * 32 + quad * 8];
        bf16x8 a1 = *(const bf16x8*)&Ab[buf][(wave * 32 + 16 + col) * 32 + quad * 8];
        __builtin_amdgcn_s_setprio(1);
        #pragma unroll
        for (int nt = 0; nt < 4; ++nt) {
            bf16x8 b = *(const bf16x8*)&Bbuf[buf][(nt * 16 + col) * 32 + quad * 8];
            acc[0][nt] = MFMA(a0, b, acc[0][nt], 0, 0, 0);
            acc[1][nt] = MFMA(a1, b, acc[1][nt], 0, 0, 0);
        }
        __builtin_amdgcn_s_setprio(0);
        __syncthreads();
    }

    #pragma unroll
    for (int rt = 0; rt < 2; ++rt)
        #pragma unroll
        for (int nt = 0; nt < 4; ++nt)
            #pragma unroll
            for (int r = 0; r < 4; ++r) {
                int m = m0b + wave * 32 + rt * 16 + quad * 4 + r;
                out[(size_t)m * DM + n0 + nt * 16 + col] = acc[rt][nt][r];
            }
}

// ---------- flash attention, cooperative LDS KV staging + swapped-QK^T.
// Block = 64 q-rows (4 waves x 16). All 4 waves share an IDENTICAL KV tile list
// ((i0+16w-511)&~63 is w-invariant), so K/V tiles are staged once per block into
// double-buffered LDS (reg-staged: loads issued at iter top, ds_write after
// compute, one barrier per tile). Lane owns q-row i=i0+col (swapped MFMA);
// P^T rebuilt in-register via 8 cvt_pk + 16 bpermute + 8 cndmask per tile.
__global__ __launch_bounds__(256) void k_attn(const unsigned short* __restrict__ Q,
                                              const unsigned short* __restrict__ K,
                                              const unsigned short* __restrict__ Vt,
                                              unsigned short* __restrict__ AO) {
    __shared__ __align__(16) unsigned short kbuf[2][64 * 64]; // [buf][j][d] 8KB
    __shared__ __align__(16) unsigned short vbuf[2][64 * 64]; // [buf][d][j] 8KB
    const int lane = threadIdx.x & 63;
    const int wave = threadIdx.x >> 6;
    const int quad = lane >> 4, col = lane & 15;
    // bijective XCD swizzle: 768 blocks = 8 XCDs x 96
    const int lbid = (blockIdx.x & 7) * 96 + (blockIdx.x >> 3);
    const int qb = lbid & 31, bh = lbid >> 5;
    const int h = bh % HH, b = bh / HH;
    const int hkv = h / 3;
    const int i0 = qb * 64 + wave * 16;
    const int irow = i0 + col;

    const unsigned short* qbase = Q + ((size_t)(b * HH + h) * TT + irow) * DH + quad * 8;
    const bf16x8 qf0 = *(const bf16x8*)qbase;
    const bf16x8 qf1 = *(const bf16x8*)(qbase + 32);
    const unsigned short* kbase = K + (size_t)(b * HKV + hkv) * TT * DH;
    const unsigned short* vbase = Vt + (size_t)(b * HKV + hkv) * DH * TT;

    float m_run = -1e30f, l_lane = 0.f;
    f32x4 accO[4];
    #pragma unroll
    for (int dt = 0; dt < 4; ++dt) accO[dt] = f32x4{0.f, 0.f, 0.f, 0.f};

    // block-uniform tile list (identical for all 4 waves)
    int jw0 = (qb * 64 - WIN + 1) & ~63; if (jw0 < 64) jw0 = 64;
    const int jlast = qb * 64;
    const int nt = 1 + ((jlast >= 64) ? (((jlast - jw0) >> 6) + 1) : 0);
    auto j0_of = [&](int t) { return (t == 0) ? 0 : (jw0 + ((t - 1) << 6)); };

    // staging geometry: wave stages K rows [16w,16w+16) and V d-rows [16w,16w+16)
    const int srow = wave * 16 + (lane >> 3);
    const int sq = lane & 7;

    // bpermute source byte-addresses (lane*4) for P^T gather
    const int L0 = ((((quad * 2) & 3) << 4) | col) << 2;
    const int L1 = ((((quad * 2 + 1) & 3) << 4) | col) << 2;
    const bool hiq = quad >= 2;

    uint4 g0, g1, g2, g3;
    auto stage_load = [&](int j0) {
        const unsigned short* ks = kbase + (size_t)(j0 + srow) * DH + sq * 8;
        const unsigned short* vs = vbase + (size_t)srow * TT + j0 + sq * 8;
        g0 = *(const uint4*)ks;
        g1 = *(const uint4*)(ks + 8 * DH);
        g2 = *(const uint4*)vs;
        g3 = *(const uint4*)(vs + 8 * TT);
    };
    auto stage_write = [&](int bb) {
        unsigned short* kd = &kbuf[bb][srow * 64 + sq * 8];
        unsigned short* vd = &vbuf[bb][srow * 64 + sq * 8];
        *(uint4*)kd = g0;
        *(uint4*)(kd + 8 * 64) = g1;
        *(uint4*)vd = g2;
        *(uint4*)(vd + 8 * 64) = g3;
    };

    stage_load(0);
    stage_write(0);
    __syncthreads();

    for (int t = 0; t < nt; ++t) {
        const int bb = t & 1;
        const bool more = (t + 1) < nt;
        if (more) stage_load(j0_of(t + 1));   // issue-early (T14)

        const int j0 = j0_of(t);
        const int mode = (t == 0) ? ((i0 < 64) ? 1 : 0)
                       : (((j0 + 63 > i0) || (j0 <= i0 + 15 - WIN)) ? 2 : 0);

        // QK^T (swapped): sT[f][r] = S[irow][j0+f*16+quad*4+r]
        f32x4 sT[4];
        #pragma unroll
        for (int f = 0; f < 4; ++f) sT[f] = f32x4{0.f, 0.f, 0.f, 0.f};
        __builtin_amdgcn_s_setprio(1);
        #pragma unroll
        for (int f = 0; f < 4; ++f) {
            bf16x8 k0 = *(const bf16x8*)&kbuf[bb][(f * 16 + col) * 64 + quad * 8];
            bf16x8 k1 = *(const bf16x8*)&kbuf[bb][(f * 16 + col) * 64 + 32 + quad * 8];
            sT[f] = MFMA(k0, qf0, sT[f], 0, 0, 0);
            sT[f] = MFMA(k1, qf1, sT[f], 0, 0, 0);
        }
        __builtin_amdgcn_s_setprio(0);

        const int dq = irow - j0 - quad * 4;  // d = dq - f*16 - r
        if (mode == 1) {
            #pragma unroll
            for (int f = 0; f < 4; ++f)
                #pragma unroll
                for (int r = 0; r < 4; ++r)
                    if (dq - f * 16 - r < 0) sT[f][r] = -3e30f;
        } else if (mode == 2) {
            #pragma unroll
            for (int f = 0; f < 4; ++f)
                #pragma unroll
                for (int r = 0; r < 4; ++r)
                    if ((unsigned)(dq - f * 16 - r) >= (unsigned)WIN) sT[f][r] = -3e30f;
        }

        float mx = -3e30f;
        #pragma unroll
        for (int f = 0; f < 4; ++f)
            #pragma unroll
            for (int r = 0; r < 4; ++r) mx = fmaxf(mx, sT[f][r]);

        if (!__all(mx <= m_run + 44.f)) {     // defer-max: rare after tile 0
            float rm = fmaxf(mx, __shfl_xor(mx, 16));
            rm = fmaxf(rm, __shfl_xor(rm, 32));
            float mn = fmaxf(m_run, rm);
            float corr = exp2f((m_run - mn) * SC2);
            m_run = mn;
            l_lane *= corr;
            #pragma unroll
            for (int dt = 0; dt < 4; ++dt)
                #pragma unroll
                for (int r = 0; r < 4; ++r) accO[dt][r] *= corr;
        }

        const float mbase = m_run * SC2;
        unsigned int pk[4][2];
        float ps = 0.f;
        #pragma unroll
        for (int f = 0; f < 4; ++f) {
            float p0 = exp2f(__builtin_fmaf(sT[f][0], SC2, -mbase));
            float p1 = exp2f(__builtin_fmaf(sT[f][1], SC2, -mbase));
            float p2 = exp2f(__builtin_fmaf(sT[f][2], SC2, -mbase));
            float p3 = exp2f(__builtin_fmaf(sT[f][3], SC2, -mbase));
            ps += (p0 + p1) + (p2 + p3);
            asm("v_cvt_pk_bf16_f32 %0, %1, %2" : "=v"(pk[f][0]) : "v"(p0), "v"(p1));
            asm("v_cvt_pk_bf16_f32 %0, %1, %2" : "=v"(pk[f][1]) : "v"(p2), "v"(p3));
        }
        l_lane += ps;

        // V fragments from LDS (issued here; consumed under bpermute latency)
        bf16x8 vf[8];
        #pragma unroll
        for (int js = 0; js < 2; ++js)
            #pragma unroll
            for (int dt = 0; dt < 4; ++dt)
                vf[js * 4 + dt] =
                    *(const bf16x8*)&vbuf[bb][(dt * 16 + col) * 64 + js * 32 + quad * 8];

        // P^T redistribution + PV, js = 0 then 1
        #pragma unroll
        for (int js = 0; js < 2; ++js) {
            int fa = 2 * js, fb = 2 * js + 1;
            unsigned int a0 = __builtin_amdgcn_ds_bpermute(L0, pk[fa][0]);
            unsigned int a1 = __builtin_amdgcn_ds_bpermute(L0, pk[fa][1]);
            unsigned int a2 = __builtin_amdgcn_ds_bpermute(L1, pk[fa][0]);
            unsigned int a3 = __builtin_amdgcn_ds_bpermute(L1, pk[fa][1]);
            unsigned int b0 = __builtin_amdgcn_ds_bpermute(L0, pk[fb][0]);
            unsigned int b1 = __builtin_amdgcn_ds_bpermute(L0, pk[fb][1]);
            unsigned int b2 = __builtin_amdgcn_ds_bpermute(L1, pk[fb][0]);
            unsigned int b3 = __builtin_amdgcn_ds_bpermute(L1, pk[fb][1]);
            union { bf16x8 v; unsigned int u[4]; } pb;
            pb.u[0] = hiq ? b0 : a0;
            pb.u[1] = hiq ? b1 : a1;
            pb.u[2] = hiq ? b2 : a2;
            pb.u[3] = hiq ? b3 : a3;
            __builtin_amdgcn_s_setprio(1);
            #pragma unroll
            for (int dt = 0; dt < 4; ++dt)
                accO[dt] = MFMA(vf[js * 4 + dt], pb.v, accO[dt], 0, 0, 0);
            __builtin_amdgcn_s_setprio(0);
        }

        if (more) stage_write(bb ^ 1);        // write-late (after vmcnt drain)
        __syncthreads();
    }

    float lr = l_lane;
    lr += __shfl_xor(lr, 16);
    lr += __shfl_xor(lr, 32);
    const float inv = 1.0f / lr;

    unsigned short* dst = AO + ((size_t)b * TT + irow) * DM + h * DH + quad * 4;
    #pragma unroll
    for (int dt = 0; dt < 4; ++dt) {
        u16x4 o;
        o.x = f2b(accO[dt][0] * inv);
        o.y = f2b(accO[dt][1] * inv);
        o.z = f2b(accO[dt][2] * inv);
        o.w = f2b(accO[dt][3] * inv);
        *(u16x4*)(dst + dt * 16) = o;
    }
}

extern "C" void kernel_launch(void* const* d_in, const int* in_sizes, int n_in,
                              void* d_out, int out_size, void* d_ws, size_t ws_size,
                              hipStream_t stream) {
    const float* x  = (const float*)d_in[0];
    const float* wq = (const float*)d_in[1];
    const float* wk = (const float*)d_in[2];
    const float* wv = (const float*)d_in[3];
    const float* wo = (const float*)d_in[4];
    float* out = (float*)d_out;

    char* ws = (char*)d_ws;
    size_t off = 0;
    auto alloc = [&](size_t bytes) -> void* {
        void* p = ws + off;
        off += (bytes + 255) & ~(size_t)255;
        return p;
    };
    const int M = BB * TT; // 4096
    unsigned short* xb  = (unsigned short*)alloc((size_t)M * DM * 2);
    unsigned short* wqT = (unsigned short*)alloc((size_t)DM * DM * 2);
    unsigned short* wkT = (unsigned short*)alloc((size_t)(HKV * DH) * DM * 2);
    unsigned short* wvT = (unsigned short*)alloc((size_t)(HKV * DH) * DM * 2);
    unsigned short* woT = (unsigned short*)alloc((size_t)DM * DM * 2);
    unsigned short* qb  = (unsigned short*)alloc((size_t)BB * HH * TT * DH * 2);
    unsigned short* kb  = (unsigned short*)alloc((size_t)BB * HKV * TT * DH * 2);
    unsigned short* vtb = (unsigned short*)alloc((size_t)BB * HKV * DH * TT * 2);
    unsigned short* ao  = (unsigned short*)alloc((size_t)M * DM * 2);
    float2* rope        = (float2*)alloc((size_t)TT * 32 * sizeof(float2));

    k_prep<<<3328, 256, 0, stream>>>(x, xb, rope);
    k_tw<<<1536, 256, 0, stream>>>(wq, wk, wv, wo, wqT, wkT, wvT, woT);
    k_qkv<<<dim3(M / 128, 20), 256, 0, stream>>>(xb, wqT, wkT, wvT, qb, kb, vtb, rope);
    k_attn<<<768, 256, 0, stream>>>(qb, kb, vtb, ao);
    k_out<<<dim3(M / 128, 12), 256, 0, stream>>>(ao, woT, out);
}

// Round 7
// 61.359 us; speedup vs baseline: 2.6917x; 1.2278x over previous
//
#include <hip/hip_runtime.h>
#include <hip/hip_bf16.h>

// GQA prefill: B=2 T=2048 DM=768 H=12 HKV=4 DH=64 WIN=512 GLB=64
// 4 launches: pre(convert+rope+transpose) | fused QKV GEMM (BK=64 LDS dbuf,
// XOR-swizzled, rope fused, V transposed) | flash attn (LDS KV staging with
// XOR swizzle, swapped-QK^T, bpermute P-transpose) | out GEMM (BK=64).

typedef __attribute__((ext_vector_type(8))) short bf16x8;
typedef __attribute__((ext_vector_type(4))) float f32x4;
typedef __attribute__((ext_vector_type(4))) unsigned short u16x4;

#define MFMA __builtin_amdgcn_mfma_f32_16x16x32_bf16

constexpr int BB = 2, TT = 2048, DM = 768, HH = 12, HKV = 4, DH = 64;
constexpr int WIN = 512, GLB = 64;
constexpr float SC2 = 0.18033688011112042f; // 0.125 * log2(e)

__device__ __forceinline__ unsigned short f2b(float f) {
    union { float f; unsigned int u; } v; v.f = f;
    unsigned int r = v.u + 0x7fffu + ((v.u >> 16) & 1u);
    return (unsigned short)(r >> 16);
}

#define GLOAD_LDS(gp, lp)                                                      \
    __builtin_amdgcn_global_load_lds(                                          \
        (const __attribute__((address_space(1))) void*)(gp),                   \
        (__attribute__((address_space(3))) void*)(lp), 16, 0, 0)

// ---------- fused prep: x->bf16 (0..3071), rope (3072..3327), W^T (3328..4863)
__global__ __launch_bounds__(256) void k_pre(const float* __restrict__ x,
                                             unsigned short* __restrict__ xb,
                                             float2* __restrict__ rope,
                                             const float* __restrict__ wq,
                                             const float* __restrict__ wk,
                                             const float* __restrict__ wv,
                                             const float* __restrict__ wo,
                                             unsigned short* __restrict__ wqT,
                                             unsigned short* __restrict__ wkT,
                                             unsigned short* __restrict__ wvT,
                                             unsigned short* __restrict__ woT) {
    __shared__ float t[32][33];
    int bid = blockIdx.x, tid = threadIdx.x;
    if (bid < 3072) {
        int i = bid * 256 + tid;
        float4 v = ((const float4*)x)[i];
        u16x4 o; o.x = f2b(v.x); o.y = f2b(v.y); o.z = f2b(v.z); o.w = f2b(v.w);
        ((u16x4*)xb)[i] = o;
        return;
    }
    if (bid < 3328) {
        int i = (bid - 3072) * 256 + tid;  // T*32
        int tt = i >> 5, p = i & 31;
        float inv = exp2f(-(float)p * (13.287712379549449f / 32.0f));
        float ang = (float)tt * inv;
        rope[i] = make_float2(cosf(ang), sinf(ang));
        return;
    }
    int wb = bid - 3328;
    const float* src; unsigned short* dst; int N, tile;
    if (wb < 576)      { src = wq; dst = wqT; N = 768; tile = wb; }
    else if (wb < 768) { src = wk; dst = wkT; N = 256; tile = wb - 576; }
    else if (wb < 960) { src = wv; dst = wvT; N = 256; tile = wb - 768; }
    else               { src = wo; dst = woT; N = 768; tile = wb - 960; }
    int ntiles = N / 32;
    int k0 = (tile / ntiles) * 32, n0 = (tile % ntiles) * 32;
    int tx = tid & 31, ty = tid >> 5;
    #pragma unroll
    for (int e = 0; e < 4; ++e) {
        int r = ty + e * 8;
        t[r][tx] = src[(size_t)(k0 + r) * N + n0 + tx];
    }
    __syncthreads();
    #pragma unroll
    for (int e = 0; e < 4; ++e) {
        int r = ty + e * 8;
        dst[(size_t)(n0 + r) * DM + k0 + tx] = f2b(t[tx][r]);
    }
}

// ---------- fused QKV GEMM: 128x64 tile, BK=64, 12 steps, XOR-swizzled LDS.
// y<12 Q(rope), y<16 K(rope), else V(transposed store).
__global__ __launch_bounds__(256) void k_qkv(const unsigned short* __restrict__ xb,
                                             const unsigned short* __restrict__ wqT,
                                             const unsigned short* __restrict__ wkT,
                                             const unsigned short* __restrict__ wvT,
                                             unsigned short* __restrict__ qb,
                                             unsigned short* __restrict__ kb,
                                             unsigned short* __restrict__ vtb,
                                             const float2* __restrict__ rope) {
    __shared__ __align__(16) unsigned short Ab[2][128 * 64]; // 16KB per buf
    __shared__ __align__(16) unsigned short Bb[2][64 * 64];  // 8KB per buf
    const int tid = threadIdx.x;
    const int wave = tid >> 6, lane = tid & 63;
    const int quad = lane >> 4, col = lane & 15;
    const int y = blockIdx.y;
    int mode, hl;
    const unsigned short* Bt;
    if (y < 12)      { mode = 0; hl = y;      Bt = wqT + (size_t)hl * 64 * DM; }
    else if (y < 16) { mode = 1; hl = y - 12; Bt = wkT + (size_t)hl * 64 * DM; }
    else             { mode = 2; hl = y - 16; Bt = wvT + (size_t)hl * 64 * DM; }
    const int m0b = blockIdx.x * 128;

    // staging: lane covers (row = g*8 + lane>>3, physical chunk = lane&7);
    // source chunk pre-swizzled so LDS-linear dest yields swizzled layout
    const int rg = lane >> 3;                 // 0..7
    const int cg = (lane & 7) ^ rg;           // source 16B chunk
    const int ck = col & 7;                   // read-side XOR key

    f32x4 acc[2][4];
    #pragma unroll
    for (int rt = 0; rt < 2; ++rt)
        #pragma unroll
        for (int j = 0; j < 4; ++j) acc[rt][j] = f32x4{0.f, 0.f, 0.f, 0.f};

    auto stage = [&](int buf, int k) {
        #pragma unroll
        for (int m = 0; m < 4; ++m) {
            int g = wave * 4 + m;             // 16 groups x 8 rows = 128 A rows
            GLOAD_LDS(xb + (size_t)(m0b + g * 8 + rg) * DM + k + cg * 8,
                      &Ab[buf][g * 512]);
        }
        #pragma unroll
        for (int m = 0; m < 2; ++m) {
            int g = wave * 2 + m;             // 8 groups x 8 rows = 64 B rows
            GLOAD_LDS(Bt + (size_t)(g * 8 + rg) * DM + k + cg * 8,
                      &Bb[buf][g * 512]);
        }
    };

    stage(0, 0);
    __syncthreads();

    const int arow0 = (wave * 32 + col) * 64;
    const int arow1 = (wave * 32 + 16 + col) * 64;

    for (int t = 0; t < 12; ++t) {
        const int buf = t & 1;
        if (t < 11) stage(buf ^ 1, (t + 1) * 64);
        __builtin_amdgcn_s_setprio(1);
        #pragma unroll
        for (int ks = 0; ks < 2; ++ks) {
            const int p = ((ks * 4 + quad) ^ ck) * 8;
            bf16x8 a0 = *(const bf16x8*)&Ab[buf][arow0 + p];
            bf16x8 a1 = *(const bf16x8*)&Ab[buf][arow1 + p];
            #pragma unroll
            for (int j = 0; j < 4; ++j) {
                bf16x8 b = *(const bf16x8*)&Bb[buf][(j * 16 + col) * 64 + p];
                acc[0][j] = MFMA(a0, b, acc[0][j], 0, 0, 0);
                acc[1][j] = MFMA(a1, b, acc[1][j], 0, 0, 0);
            }
        }
        __builtin_amdgcn_s_setprio(0);
        __syncthreads();   // drains vmcnt (next tile staged) + lgkm
    }

    if (mode == 2) {
        int b = m0b >> 11;
        #pragma unroll
        for (int j = 0; j < 4; ++j)
            #pragma unroll
            for (int rt = 0; rt < 2; ++rt)
                #pragma unroll
                for (int r = 0; r < 4; ++r) {
                    int m = m0b + wave * 32 + rt * 16 + quad * 4 + r;
                    int t = m & (TT - 1);
                    int d = j * 16 + col;
                    vtb[((size_t)(b * HKV + hl) * DH + d) * TT + t] = f2b(acc[rt][j][r]);
                }
        return;
    }
    int nheads = (mode == 0) ? HH : HKV;
    unsigned short* ob = (mode == 0) ? qb : kb;
    #pragma unroll
    for (int rt = 0; rt < 2; ++rt)
        #pragma unroll
        for (int r = 0; r < 4; ++r) {
            int m = m0b + wave * 32 + rt * 16 + quad * 4 + r;
            int t = m & (TT - 1);
            int b = m >> 11;
            float2 cs0 = rope[t * 32 + col];
            float2 cs1 = rope[t * 32 + 16 + col];
            float v0 = acc[rt][0][r], v1 = acc[rt][1][r], v2 = acc[rt][2][r], v3 = acc[rt][3][r];
            unsigned short* dst = ob + ((size_t)(b * nheads + hl) * TT + t) * DH + col;
            dst[0]  = f2b(v0 * cs0.x - v2 * cs0.y);
            dst[16] = f2b(v1 * cs1.x - v3 * cs1.y);
            dst[32] = f2b(v2 * cs0.x + v0 * cs0.y);
            dst[48] = f2b(v3 * cs1.x + v1 * cs1.y);
        }
}

// ---------- output projection GEMM (f32 out), same BK=64 staged structure
__global__ __launch_bounds__(256) void k_out(const unsigned short* __restrict__ ao,
                                             const unsigned short* __restrict__ woT,
                                             float* __restrict__ out) {
    __shared__ __align__(16) unsigned short Ab[2][128 * 64];
    __shared__ __align__(16) unsigned short Bb[2][64 * 64];
    const int tid = threadIdx.x;
    const int wave = tid >> 6, lane = tid & 63;
    const int quad = lane >> 4, col = lane & 15;
    const int m0b = blockIdx.x * 128;
    const int n0 = blockIdx.y * 64;

    const int rg = lane >> 3;
    const int cg = (lane & 7) ^ rg;
    const int ck = col & 7;

    f32x4 acc[2][4];
    #pragma unroll
    for (int rt = 0; rt < 2; ++rt)
        #pragma unroll
        for (int j = 0; j < 4; ++j) acc[rt][j] = f32x4{0.f, 0.f, 0.f, 0.f};

    auto stage = [&](int buf, int k) {
        #pragma unroll
        for (int m = 0; m < 4; ++m) {
            int g = wave * 4 + m;
            GLOAD_LDS(ao + (size_t)(m0b + g * 8 + rg) * DM + k + cg * 8,
                      &Ab[buf][g * 512]);
        }
        #pragma unroll
        for (int m = 0; m < 2; ++m) {
            int g = wave * 2 + m;
            GLOAD_LDS(woT + (size_t)(n0 + g * 8 + rg) * DM + k + cg * 8,
                      &Bb[buf][g * 512]);
        }
    };

    stage(0, 0);
    __syncthreads();

    const int arow0 = (wave * 32 + col) * 64;
    const int arow1 = (wave * 32 + 16 + col) * 64;

    for (int t = 0; t < 12; ++t) {
        const int buf = t & 1;
        if (t < 11) stage(buf ^ 1, (t + 1) * 64);
        __builtin_amdgcn_s_setprio(1);
        #pragma unroll
        for (int ks = 0; ks < 2; ++ks) {
            const int p = ((ks * 4 + quad) ^ ck) * 8;
            bf16x8 a0 = *(const bf16x8*)&Ab[buf][arow0 + p];
            bf16x8 a1 = *(const bf16x8*)&Ab[buf][arow1 + p];
            #pragma unroll
            for (int j = 0; j < 4; ++j) {
                bf16x8 b = *(const bf16x8*)&Bb[buf][(j * 16 + col) * 64 + p];
                acc[0][j] = MFMA(a0, b, acc[0][j], 0, 0, 0);
                acc[1][j] = MFMA(a1, b, acc[1][j], 0, 0, 0);
            }
        }
        __builtin_amdgcn_s_setprio(0);
        __syncthreads();
    }

    #pragma unroll
    for (int rt = 0; rt < 2; ++rt)
        #pragma unroll
        for (int j = 0; j < 4; ++j)
            #pragma unroll
            for (int r = 0; r < 4; ++r) {
                int m = m0b + wave * 32 + rt * 16 + quad * 4 + r;
                out[(size_t)m * DM + n0 + j * 16 + col] = acc[rt][j][r];
            }
}

// ---------- flash attention, LDS KV staging (XOR-swizzled) + swapped-QK^T.
// kbuf/vbuf rows are 128B; physical chunk p stores logical chunk p^(row&7).
// Reads at logical chunk c use p = c^(row&7): 16-way bank conflict -> 2-way.
__global__ __launch_bounds__(256) void k_attn(const unsigned short* __restrict__ Q,
                                              const unsigned short* __restrict__ K,
                                              const unsigned short* __restrict__ Vt,
                                              unsigned short* __restrict__ AO) {
    __shared__ __align__(16) unsigned short kbuf[2][64 * 64]; // [buf][j][d] 8KB
    __shared__ __align__(16) unsigned short vbuf[2][64 * 64]; // [buf][d][j] 8KB
    const int lane = threadIdx.x & 63;
    const int wave = threadIdx.x >> 6;
    const int quad = lane >> 4, col = lane & 15;
    // bijective XCD swizzle: 768 blocks = 8 XCDs x 96
    const int lbid = (blockIdx.x & 7) * 96 + (blockIdx.x >> 3);
    const int qb = lbid & 31, bh = lbid >> 5;
    const int h = bh % HH, b = bh / HH;
    const int hkv = h / 3;
    const int i0 = qb * 64 + wave * 16;
    const int irow = i0 + col;

    const unsigned short* qbase = Q + ((size_t)(b * HH + h) * TT + irow) * DH + quad * 8;
    const bf16x8 qf0 = *(const bf16x8*)qbase;
    const bf16x8 qf1 = *(const bf16x8*)(qbase + 32);
    const unsigned short* kbase = K + (size_t)(b * HKV + hkv) * TT * DH;
    const unsigned short* vbase = Vt + (size_t)(b * HKV + hkv) * DH * TT;

    float m_run = -1e30f, l_lane = 0.f;
    f32x4 accO[4];
    #pragma unroll
    for (int dt = 0; dt < 4; ++dt) accO[dt] = f32x4{0.f, 0.f, 0.f, 0.f};

    // block-uniform tile list (identical for all 4 waves)
    int jw0 = (qb * 64 - WIN + 1) & ~63; if (jw0 < 64) jw0 = 64;
    const int jlast = qb * 64;
    const int nt = 1 + ((jlast >= 64) ? (((jlast - jw0) >> 6) + 1) : 0);
    auto j0_of = [&](int t) { return (t == 0) ? 0 : (jw0 + ((t - 1) << 6)); };

    // staging: wave stages K rows/V d-rows [16w,16w+16); source chunk pre-swizzled
    const int srow = wave * 16 + (lane >> 3);
    const int sk = (lane >> 3) & 7;              // row&7 key (wave*16 = 0 mod 8)
    const int sq = (lane & 7) ^ sk;              // source 16B chunk
    const int ck = col & 7;                      // read key: row = *16+col

    // bpermute source byte-addresses (lane*4) for P^T gather
    const int L0 = ((((quad * 2) & 3) << 4) | col) << 2;
    const int L1 = ((((quad * 2 + 1) & 3) << 4) | col) << 2;
    const bool hiq = quad >= 2;

    uint4 g0, g1, g2, g3;
    auto stage_load = [&](int j0) {
        const unsigned short* ks = kbase + (size_t)(j0 + srow) * DH + sq * 8;
        const unsigned short* vs = vbase + (size_t)srow * TT + j0 + sq * 8;
        g0 = *(const uint4*)ks;
        g1 = *(const uint4*)(ks + 8 * DH);       // row srow+8: same &7 key
        g2 = *(const uint4*)vs;
        g3 = *(const uint4*)(vs + 8 * TT);
    };
    auto stage_write = [&](int bb) {
        unsigned short* kd = &kbuf[bb][srow * 64 + (lane & 7) * 8];
        unsigned short* vd = &vbuf[bb][srow * 64 + (lane & 7) * 8];
        *(uint4*)kd = g0;
        *(uint4*)(kd + 8 * 64) = g1;
        *(uint4*)vd = g2;
        *(uint4*)(vd + 8 * 64) = g3;
    };

    stage_load(0);
    stage_write(0);
    __syncthreads();

    for (int t = 0; t < nt; ++t) {
        const int bb = t & 1;
        const bool more = (t + 1) < nt;
        if (more) stage_load(j0_of(t + 1));   // issue-early (T14)

        const int j0 = j0_of(t);
        const int mode = (t == 0) ? ((i0 < 64) ? 1 : 0)
                       : (((j0 + 63 > i0) || (j0 <= i0 + 15 - WIN)) ? 2 : 0);

        // QK^T (swapped): sT[f][r] = S[irow][j0+f*16+quad*4+r]
        f32x4 sT[4];
        #pragma unroll
        for (int f = 0; f < 4; ++f) sT[f] = f32x4{0.f, 0.f, 0.f, 0.f};
        __builtin_amdgcn_s_setprio(1);
        #pragma unroll
        for (int f = 0; f < 4; ++f) {
            bf16x8 k0 = *(const bf16x8*)&kbuf[bb][(f * 16 + col) * 64 + (quad ^ ck) * 8];
            bf16x8 k1 = *(const bf16x8*)&kbuf[bb][(f * 16 + col) * 64 + ((4 + quad) ^ ck) * 8];
            sT[f] = MFMA(k0, qf0, sT[f], 0, 0, 0);
            sT[f] = MFMA(k1, qf1, sT[f], 0, 0, 0);
        }
        __builtin_amdgcn_s_setprio(0);

        const int dq = irow - j0 - quad * 4;  // d = dq - f*16 - r
        if (mode == 1) {
            #pragma unroll
            for (int f = 0; f < 4; ++f)
                #pragma unroll
                for (int r = 0; r < 4; ++r)
                    if (dq - f * 16 - r < 0) sT[f][r] = -3e30f;
        } else if (mode == 2) {
            #pragma unroll
            for (int f = 0; f < 4; ++f)
                #pragma unroll
                for (int r = 0; r < 4; ++r)
                    if ((unsigned)(dq - f * 16 - r) >= (unsigned)WIN) sT[f][r] = -3e30f;
        }

        float mx = -3e30f;
        #pragma unroll
        for (int f = 0; f < 4; ++f)
            #pragma unroll
            for (int r = 0; r < 4; ++r) mx = fmaxf(mx, sT[f][r]);

        if (!__all(mx <= m_run + 44.f)) {     // defer-max: rare after tile 0
            float rm = fmaxf(mx, __shfl_xor(mx, 16));
            rm = fmaxf(rm, __shfl_xor(rm, 32));
            float mn = fmaxf(m_run, rm);
            float corr = exp2f((m_run - mn) * SC2);
            m_run = mn;
            l_lane *= corr;
            #pragma unroll
            for (int dt = 0; dt < 4; ++dt)
                #pragma unroll
                for (int r = 0; r < 4; ++r) accO[dt][r] *= corr;
        }

        const float mbase = m_run * SC2;
        unsigned int pk[4][2];
        float ps = 0.f;
        #pragma unroll
        for (int f = 0; f < 4; ++f) {
            float p0 = exp2f(__builtin_fmaf(sT[f][0], SC2, -mbase));
            float p1 = exp2f(__builtin_fmaf(sT[f][1], SC2, -mbase));
            float p2 = exp2f(__builtin_fmaf(sT[f][2], SC2, -mbase));
            float p3 = exp2f(__builtin_fmaf(sT[f][3], SC2, -mbase));
            ps += (p0 + p1) + (p2 + p3);
            asm("v_cvt_pk_bf16_f32 %0, %1, %2" : "=v"(pk[f][0]) : "v"(p0), "v"(p1));
            asm("v_cvt_pk_bf16_f32 %0, %1, %2" : "=v"(pk[f][1]) : "v"(p2), "v"(p3));
        }
        l_lane += ps;

        // V fragments from LDS (swizzled; issued here, consumed under bpermute)
        bf16x8 vf[8];
        #pragma unroll
        for (int js = 0; js < 2; ++js)
            #pragma unroll
            for (int dt = 0; dt < 4; ++dt)
                vf[js * 4 + dt] = *(const bf16x8*)
                    &vbuf[bb][(dt * 16 + col) * 64 + ((js * 4 + quad) ^ ck) * 8];

        // P^T redistribution + PV, js = 0 then 1
        #pragma unroll
        for (int js = 0; js < 2; ++js) {
            int fa = 2 * js, fb = 2 * js + 1;
            unsigned int a0 = __builtin_amdgcn_ds_bpermute(L0, pk[fa][0]);
            unsigned int a1 = __builtin_amdgcn_ds_bpermute(L0, pk[fa][1]);
            unsigned int a2 = __builtin_amdgcn_ds_bpermute(L1, pk[fa][0]);
            unsigned int a3 = __builtin_amdgcn_ds_bpermute(L1, pk[fa][1]);
            unsigned int b0 = __builtin_amdgcn_ds_bpermute(L0, pk[fb][0]);
            unsigned int b1 = __builtin_amdgcn_ds_bpermute(L0, pk[fb][1]);
            unsigned int b2 = __builtin_amdgcn_ds_bpermute(L1, pk[fb][0]);
            unsigned int b3 = __builtin_amdgcn_ds_bpermute(L1, pk[fb][1]);
            union { bf16x8 v; unsigned int u[4]; } pb;
            pb.u[0] = hiq ? b0 : a0;
            pb.u[1] = hiq ? b1 : a1;
            pb.u[2] = hiq ? b2 : a2;
            pb.u[3] = hiq ? b3 : a3;
            __builtin_amdgcn_s_setprio(1);
            #pragma unroll
            for (int dt = 0; dt < 4; ++dt)
                accO[dt] = MFMA(vf[js * 4 + dt], pb.v, accO[dt], 0, 0, 0);
            __builtin_amdgcn_s_setprio(0);
        }

        if (more) stage_write(bb ^ 1);        // write-late (after vmcnt drain)
        __syncthreads();
    }

    float lr = l_lane;
    lr += __shfl_xor(lr, 16);
    lr += __shfl_xor(lr, 32);
    const float inv = 1.0f / lr;

    unsigned short* dst = AO + ((size_t)b * TT + irow) * DM + h * DH + quad * 4;
    #pragma unroll
    for (int dt = 0; dt < 4; ++dt) {
        u16x4 o;
        o.x = f2b(accO[dt][0] * inv);
        o.y = f2b(accO[dt][1] * inv);
        o.z = f2b(accO[dt][2] * inv);
        o.w = f2b(accO[dt][3] * inv);
        *(u16x4*)(dst + dt * 16) = o;
    }
}

extern "C" void kernel_launch(void* const* d_in, const int* in_sizes, int n_in,
                              void* d_out, int out_size, void* d_ws, size_t ws_size,
                              hipStream_t stream) {
    const float* x  = (const float*)d_in[0];
    const float* wq = (const float*)d_in[1];
    const float* wk = (const float*)d_in[2];
    const float* wv = (const float*)d_in[3];
    const float* wo = (const float*)d_in[4];
    float* out = (float*)d_out;

    char* ws = (char*)d_ws;
    size_t off = 0;
    auto alloc = [&](size_t bytes) -> void* {
        void* p = ws + off;
        off += (bytes + 255) & ~(size_t)255;
        return p;
    };
    const int M = BB * TT; // 4096
    unsigned short* xb  = (unsigned short*)alloc((size_t)M * DM * 2);
    unsigned short* wqT = (unsigned short*)alloc((size_t)DM * DM * 2);
    unsigned short* wkT = (unsigned short*)alloc((size_t)(HKV * DH) * DM * 2);
    unsigned short* wvT = (unsigned short*)alloc((size_t)(HKV * DH) * DM * 2);
    unsigned short* woT = (unsigned short*)alloc((size_t)DM * DM * 2);
    unsigned short* qb  = (unsigned short*)alloc((size_t)BB * HH * TT * DH * 2);
    unsigned short* kb  = (unsigned short*)alloc((size_t)BB * HKV * TT * DH * 2);
    unsigned short* vtb = (unsigned short*)alloc((size_t)BB * HKV * DH * TT * 2);
    unsigned short* ao  = (unsigned short*)alloc((size_t)M * DM * 2);
    float2* rope        = (float2*)alloc((size_t)TT * 32 * sizeof(float2));

    k_pre<<<4864, 256, 0, stream>>>(x, xb, rope, wq, wk, wv, wo, wqT, wkT, wvT, woT);
    k_qkv<<<dim3(M / 128, 20), 256, 0, stream>>>(xb, wqT, wkT, wvT, qb, kb, vtb, rope);
    k_attn<<<768, 256, 0, stream>>>(qb, kb, vtb, ao);
    k_out<<<dim3(M / 128, 12), 256, 0, stream>>>(ao, woT, out);
}